// Round 1
// baseline (873.255 us; speedup 1.0000x reference)
//
#include <hip/hip_runtime.h>
#include <hip/hip_bf16.h>

typedef __bf16 bf16;
typedef __attribute__((ext_vector_type(8))) __bf16 bf16x8;
typedef __attribute__((ext_vector_type(4))) float f32x4;

#define MFMA16(a, b, c) __builtin_amdgcn_mfma_f32_16x16x32_bf16((a), (b), (c), 0, 0, 0)

// ---------------------------------------------------------------------------
// Kernel 1: weight transpose + f32->bf16 cast.  W [1024(k)][1024(n)] f32 ->
// Wt [1024(n)][1024(k)] bf16, so MFMA B-fragments are contiguous 16B loads.
// ---------------------------------------------------------------------------
__global__ __launch_bounds__(256) void wcvt_kernel(
    const float* __restrict__ W0, const float* __restrict__ W1,
    const float* __restrict__ W2, const float* __restrict__ W3,
    bf16* __restrict__ T0, bf16* __restrict__ T1,
    bf16* __restrict__ T2, bf16* __restrict__ T3)
{
    const int z = blockIdx.z;
    const float* W = (z == 0) ? W0 : (z == 1) ? W1 : (z == 2) ? W2 : W3;
    bf16* T = (z == 0) ? T0 : (z == 1) ? T1 : (z == 2) ? T2 : T3;
    const int k0 = blockIdx.x * 64, n0 = blockIdx.y * 64;
    const int tid = threadIdx.x;

    __shared__ float tile[64][65];   // +1 pad breaks bank conflicts on column reads

    #pragma unroll
    for (int rr = 0; rr < 4; ++rr) {
        int r = (tid >> 4) + rr * 16;      // 0..63 (k-local)
        int cg = (tid & 15) * 4;           // 0..60 (n-local)
        float4 v = *(const float4*)(W + (size_t)(k0 + r) * 1024 + n0 + cg);
        tile[r][cg + 0] = v.x; tile[r][cg + 1] = v.y;
        tile[r][cg + 2] = v.z; tile[r][cg + 3] = v.w;
    }
    __syncthreads();

    const int n_local = tid >> 2;          // 0..63
    const int kg = (tid & 3) * 16;         // 0,16,32,48
    bf16x8 v0, v1;
    #pragma unroll
    for (int j = 0; j < 8; ++j) v0[j] = (bf16)tile[kg + j][n_local];
    #pragma unroll
    for (int j = 0; j < 8; ++j) v1[j] = (bf16)tile[kg + 8 + j][n_local];
    bf16* dst = T + (size_t)(n0 + n_local) * 1024 + k0 + kg;
    *(bf16x8*)dst = v0;
    *(bf16x8*)(dst + 8) = v1;
}

// ---------------------------------------------------------------------------
// Kernel 2: QKV projection.  X [4096][1024] f32  @  Wt [1024(n)][1024(k)] bf16
//  -> Q,K as [b][h][s][64] bf16 ; V transposed as [b][h][64][s] bf16.
// Block = 256 thr (4 waves), tile 64(m) x 64(n), n-tile == one head.
// No LDS: A fragments converted in-register, B fragments L1-shared across waves.
// ---------------------------------------------------------------------------
__global__ __launch_bounds__(256) void qkv_proj(
    const float* __restrict__ Xq, const float* __restrict__ Xk, const float* __restrict__ Xv,
    const bf16* __restrict__ Wtq, const bf16* __restrict__ Wtk, const bf16* __restrict__ Wtv,
    bf16* __restrict__ Qb, bf16* __restrict__ Kb, bf16* __restrict__ VT)
{
    const int z = blockIdx.z;
    const float* X = (z == 0) ? Xq : (z == 1) ? Xk : Xv;
    const bf16* Wt = (z == 0) ? Wtq : (z == 1) ? Wtk : Wtv;
    const int h = blockIdx.x;              // 16 n-tiles == 16 heads
    const int m0 = blockIdx.y * 64;        // row tile over B*S = 4096
    const int tid = threadIdx.x, w = tid >> 6, lane = tid & 63;
    const int quad = lane >> 4, c = lane & 15;

    const float* arow = X + (size_t)(m0 + w * 16 + c) * 1024;
    const bf16* bbase = Wt + (size_t)(h * 64) * 1024;

    f32x4 acc[4];
    #pragma unroll
    for (int ct = 0; ct < 4; ++ct) acc[ct] = (f32x4){0.f, 0.f, 0.f, 0.f};

    for (int k0 = 0; k0 < 1024; k0 += 32) {
        const float* p = arow + k0 + quad * 8;
        float4 u = *(const float4*)p;
        float4 v = *(const float4*)(p + 4);
        bf16x8 af = {(bf16)u.x, (bf16)u.y, (bf16)u.z, (bf16)u.w,
                     (bf16)v.x, (bf16)v.y, (bf16)v.z, (bf16)v.w};
        #pragma unroll
        for (int ct = 0; ct < 4; ++ct) {
            bf16x8 bv = *(const bf16x8*)(bbase + (size_t)(ct * 16 + c) * 1024 + k0 + quad * 8);
            acc[ct] = MFMA16(af, bv, acc[ct]);
        }
    }

    const int b = m0 >> 10;
    const int sbase = (m0 & 1023) + w * 16 + quad * 4;
    #pragma unroll
    for (int ct = 0; ct < 4; ++ct) {
        #pragma unroll
        for (int i = 0; i < 4; ++i) {
            const int d = ct * 16 + c;
            const int s = sbase + i;
            const bf16 val = (bf16)acc[ct][i];
            if (z == 0)      Qb[((size_t)(b * 16 + h) * 1024 + s) * 64 + d] = val;
            else if (z == 1) Kb[((size_t)(b * 16 + h) * 1024 + s) * 64 + d] = val;
            else             VT[((size_t)(b * 16 + h) * 64 + d) * 1024 + s] = val;
        }
    }
}

// ---------------------------------------------------------------------------
// Kernel 3: attention.  Per block: 64 q-rows x all 1024 keys for one (b,h).
// Pass 1: QK^T -> row sums of exp (no max-sub: scores bounded ~|9|).
// Pass 2: recompute QK^T, write normalized attn (f32), transpose exp(S) tile
// through per-wave LDS into MFMA-A layout, accumulate context = E @ V, /l.
// ---------------------------------------------------------------------------
__global__ __launch_bounds__(256) void attn_kernel(
    const bf16* __restrict__ Qb, const bf16* __restrict__ Kb, const bf16* __restrict__ VT,
    const float* __restrict__ lps, const unsigned char* __restrict__ mask,
    const float* __restrict__ cwp, const float* __restrict__ cbp,
    float* __restrict__ attn, bf16* __restrict__ ctxb)
{
    const int qt = blockIdx.x, h = blockIdx.y, b = blockIdx.z;
    const int tid = threadIdx.x, w = tid >> 6, lane = tid & 63;
    const int quad = lane >> 4, c = lane & 15;
    const float cw = cwp[0], cb = cbp[0];
    const int q0 = qt * 64 + w * 16;
    const size_t bh = (size_t)(b * 16 + h);

    const bf16* qptr = Qb + (bh * 1024 + q0 + c) * 64;
    const bf16x8 qf0 = *(const bf16x8*)(qptr + quad * 8);
    const bf16x8 qf1 = *(const bf16x8*)(qptr + 32 + quad * 8);
    const bf16* kbase = Kb + bh * 1024 * 64;
    const bf16* vbase = VT + bh * 64 * 1024;
    const unsigned char* mbase = mask + (size_t)b * 1024 * 1024;

    int qrow[4];
    #pragma unroll
    for (int i = 0; i < 4; ++i) qrow[i] = q0 + quad * 4 + i;

    // ---- pass 1: row sums of exp(score) ----
    float sums[4] = {0.f, 0.f, 0.f, 0.f};
    for (int kt = 0; kt < 64; ++kt) {
        const int col = kt * 16 + c;
        const bf16* kr = kbase + (size_t)col * 64;
        bf16x8 kf0 = *(const bf16x8*)(kr + quad * 8);
        bf16x8 kf1 = *(const bf16x8*)(kr + 32 + quad * 8);
        f32x4 sacc = {0.f, 0.f, 0.f, 0.f};
        sacc = MFMA16(qf0, kf0, sacc);
        sacc = MFMA16(qf1, kf1, sacc);
        #pragma unroll
        for (int i = 0; i < 4; ++i) {
            float sc = sacc[i] * 0.125f + cw * lps[(size_t)qrow[i] * 1024 + col] + cb;
            if (mbase[(size_t)qrow[i] * 1024 + col]) sc = -1e9f;
            sums[i] += __expf(sc);
        }
    }
    #pragma unroll
    for (int i = 0; i < 4; ++i) {
        #pragma unroll
        for (int m = 1; m < 16; m <<= 1) sums[i] += __shfl_xor(sums[i], m, 16);
    }
    float rl[4];
    #pragma unroll
    for (int i = 0; i < 4; ++i) rl[i] = 1.0f / sums[i];

    // ---- pass 2: write attn + PV ----
    __shared__ bf16 P[4][16][32];   // per-wave D-layout -> A-layout transpose
    f32x4 ctx[4];
    #pragma unroll
    for (int ct = 0; ct < 4; ++ct) ctx[ct] = (f32x4){0.f, 0.f, 0.f, 0.f};
    float* abase = attn + bh * 1024 * 1024;

    for (int kb = 0; kb < 32; ++kb) {
        #pragma unroll
        for (int sub = 0; sub < 2; ++sub) {
            const int col = kb * 32 + sub * 16 + c;
            const bf16* kr = kbase + (size_t)col * 64;
            bf16x8 kf0 = *(const bf16x8*)(kr + quad * 8);
            bf16x8 kf1 = *(const bf16x8*)(kr + 32 + quad * 8);
            f32x4 sacc = {0.f, 0.f, 0.f, 0.f};
            sacc = MFMA16(qf0, kf0, sacc);
            sacc = MFMA16(qf1, kf1, sacc);
            #pragma unroll
            for (int i = 0; i < 4; ++i) {
                float sc = sacc[i] * 0.125f + cw * lps[(size_t)qrow[i] * 1024 + col] + cb;
                if (mbase[(size_t)qrow[i] * 1024 + col]) sc = -1e9f;
                float e = __expf(sc);
                abase[(size_t)qrow[i] * 1024 + col] = e * rl[i];
                P[w][quad * 4 + i][sub * 16 + c] = (bf16)e;
            }
        }
        __syncthreads();
        bf16x8 pf = *(const bf16x8*)&P[w][c][quad * 8];
        #pragma unroll
        for (int ct = 0; ct < 4; ++ct) {
            bf16x8 vf = *(const bf16x8*)(vbase + (size_t)(ct * 16 + c) * 1024 + kb * 32 + quad * 8);
            ctx[ct] = MFMA16(pf, vf, ctx[ct]);
        }
        __syncthreads();
    }

    #pragma unroll
    for (int ct = 0; ct < 4; ++ct) {
        #pragma unroll
        for (int i = 0; i < 4; ++i) {
            float v = ctx[ct][i] * rl[i];
            ctxb[((size_t)b * 1024 + qrow[i]) * 1024 + h * 64 + ct * 16 + c] = (bf16)v;
        }
    }
}

// ---------------------------------------------------------------------------
// Kernel 4: out_pre = ctx @ W_fc + input_Q   (f32 out, pre-LayerNorm)
// ---------------------------------------------------------------------------
__global__ __launch_bounds__(256) void fc_out(
    const bf16* __restrict__ ctxb, const bf16* __restrict__ Wt,
    const float* __restrict__ resid, float* __restrict__ outp)
{
    const int n0 = blockIdx.x * 64, m0 = blockIdx.y * 64;
    const int tid = threadIdx.x, w = tid >> 6, lane = tid & 63;
    const int quad = lane >> 4, c = lane & 15;

    const bf16* arow = ctxb + (size_t)(m0 + w * 16 + c) * 1024;
    const bf16* bbase = Wt + (size_t)n0 * 1024;

    f32x4 acc[4];
    #pragma unroll
    for (int ct = 0; ct < 4; ++ct) acc[ct] = (f32x4){0.f, 0.f, 0.f, 0.f};

    for (int k0 = 0; k0 < 1024; k0 += 32) {
        bf16x8 af = *(const bf16x8*)(arow + k0 + quad * 8);
        #pragma unroll
        for (int ct = 0; ct < 4; ++ct) {
            bf16x8 bv = *(const bf16x8*)(bbase + (size_t)(ct * 16 + c) * 1024 + k0 + quad * 8);
            acc[ct] = MFMA16(af, bv, acc[ct]);
        }
    }

    #pragma unroll
    for (int ct = 0; ct < 4; ++ct) {
        #pragma unroll
        for (int i = 0; i < 4; ++i) {
            const int r = m0 + w * 16 + quad * 4 + i;
            const int n = n0 + ct * 16 + c;
            outp[(size_t)r * 1024 + n] = acc[ct][i] + resid[(size_t)r * 1024 + n];
        }
    }
}

// ---------------------------------------------------------------------------
// Kernel 5: LayerNorm over last dim (1024), unit gamma / zero beta.
// ---------------------------------------------------------------------------
__global__ __launch_bounds__(256) void ln_kernel(
    const float* __restrict__ xp, float* __restrict__ out)
{
    const int row = blockIdx.x, tid = threadIdx.x;
    const float* p = xp + (size_t)row * 1024 + tid * 4;
    float4 x = *(const float4*)p;
    float s = x.x + x.y + x.z + x.w;
    float q = x.x * x.x + x.y * x.y + x.z * x.z + x.w * x.w;
    #pragma unroll
    for (int off = 32; off >= 1; off >>= 1) {
        s += __shfl_down(s, off);
        q += __shfl_down(q, off);
    }
    __shared__ float sb[4], qb[4];
    const int w = tid >> 6, lane = tid & 63;
    if (lane == 0) { sb[w] = s; qb[w] = q; }
    __syncthreads();
    const float ts = sb[0] + sb[1] + sb[2] + sb[3];
    const float tq = qb[0] + qb[1] + qb[2] + qb[3];
    const float mean = ts * (1.0f / 1024.0f);
    const float var = tq * (1.0f / 1024.0f) - mean * mean;
    const float rs = rsqrtf(var + 1e-5f);
    float4 o;
    o.x = (x.x - mean) * rs; o.y = (x.y - mean) * rs;
    o.z = (x.z - mean) * rs; o.w = (x.w - mean) * rs;
    *(float4*)(out + (size_t)row * 1024 + tid * 4) = o;
}

// ---------------------------------------------------------------------------
extern "C" void kernel_launch(void* const* d_in, const int* in_sizes, int n_in,
                              void* d_out, int out_size, void* d_ws, size_t ws_size,
                              hipStream_t stream)
{
    const float* Xq  = (const float*)d_in[0];
    const float* Xk  = (const float*)d_in[1];
    const float* Xv  = (const float*)d_in[2];
    const unsigned char* mask = (const unsigned char*)d_in[3];  // all-false bools
    const float* lps = (const float*)d_in[4];
    const float* Wq  = (const float*)d_in[5];
    const float* Wk  = (const float*)d_in[6];
    const float* Wv  = (const float*)d_in[7];
    const float* Wfc = (const float*)d_in[8];
    const float* cw  = (const float*)d_in[9];
    const float* cb  = (const float*)d_in[10];

    char* ws = (char*)d_ws;
    const size_t MB = 1024 * 1024;
    bf16* Wtq = (bf16*)(ws + 0 * MB);      // [1024 n][1024 k] bf16, 2MB each
    bf16* Wtk = (bf16*)(ws + 2 * MB);
    bf16* Wtv = (bf16*)(ws + 4 * MB);
    bf16* Wtf = (bf16*)(ws + 6 * MB);
    bf16* Qb  = (bf16*)(ws + 8 * MB);      // [4][16][1024][64] bf16, 8MB
    bf16* Kb  = (bf16*)(ws + 16 * MB);     // [4][16][1024][64] bf16, 8MB
    bf16* VT  = (bf16*)(ws + 24 * MB);     // [4][16][64][1024] bf16, 8MB
    bf16* ctx = (bf16*)(ws + 32 * MB);     // [4096][1024] bf16, 8MB
    float* outp = (float*)(ws + 40 * MB);  // [4096][1024] f32, 16MB

    float* out_ln = (float*)d_out;                         // [4,1024,1024] f32
    float* attn   = (float*)d_out + (size_t)4 * MB;        // [4,16,1024,1024] f32

    wcvt_kernel<<<dim3(16, 16, 4), 256, 0, stream>>>(Wq, Wk, Wv, Wfc, Wtq, Wtk, Wtv, Wtf);
    qkv_proj<<<dim3(16, 64, 3), 256, 0, stream>>>(Xq, Xk, Xv, Wtq, Wtk, Wtv, Qb, Kb, VT);
    attn_kernel<<<dim3(16, 16, 4), 256, 0, stream>>>(Qb, Kb, VT, lps, mask, cw, cb, attn, ctx);
    fc_out<<<dim3(16, 64, 1), 256, 0, stream>>>(ctx, Wtf, Xq, outp);
    ln_kernel<<<4096, 256, 0, stream>>>(outp, out_ln);
}

// Round 2
// 760.473 us; speedup vs baseline: 1.1483x; 1.1483x over previous
//
#include <hip/hip_runtime.h>
#include <hip/hip_bf16.h>

typedef __bf16 bf16;
typedef __attribute__((ext_vector_type(8))) __bf16 bf16x8;
typedef __attribute__((ext_vector_type(4))) __bf16 bf16x4;
typedef __attribute__((ext_vector_type(4))) float f32x4;

#define MFMA16(a, b, c) __builtin_amdgcn_mfma_f32_16x16x32_bf16((a), (b), (c), 0, 0, 0)

__device__ __forceinline__ void gld_lds16(const bf16* g, bf16* l) {
    __builtin_amdgcn_global_load_lds(
        (const __attribute__((address_space(1))) void*)g,
        (__attribute__((address_space(3))) void*)l, 16, 0, 0);
}

// ---------------------------------------------------------------------------
// Kernel 1: weight transpose + f32->bf16 cast.  W [1024(k)][1024(n)] f32 ->
// Wt [1024(n)][1024(k)] bf16.
// ---------------------------------------------------------------------------
__global__ __launch_bounds__(256) void wcvt_kernel(
    const float* __restrict__ W0, const float* __restrict__ W1,
    const float* __restrict__ W2, const float* __restrict__ W3,
    bf16* __restrict__ T0, bf16* __restrict__ T1,
    bf16* __restrict__ T2, bf16* __restrict__ T3)
{
    const int z = blockIdx.z;
    const float* W = (z == 0) ? W0 : (z == 1) ? W1 : (z == 2) ? W2 : W3;
    bf16* T = (z == 0) ? T0 : (z == 1) ? T1 : (z == 2) ? T2 : T3;
    const int k0 = blockIdx.x * 64, n0 = blockIdx.y * 64;
    const int tid = threadIdx.x;

    __shared__ float tile[64][65];

    #pragma unroll
    for (int rr = 0; rr < 4; ++rr) {
        int r = (tid >> 4) + rr * 16;
        int cg = (tid & 15) * 4;
        float4 v = *(const float4*)(W + (size_t)(k0 + r) * 1024 + n0 + cg);
        tile[r][cg + 0] = v.x; tile[r][cg + 1] = v.y;
        tile[r][cg + 2] = v.z; tile[r][cg + 3] = v.w;
    }
    __syncthreads();

    const int n_local = tid >> 2;
    const int kg = (tid & 3) * 16;
    bf16x8 v0, v1;
    #pragma unroll
    for (int j = 0; j < 8; ++j) v0[j] = (bf16)tile[kg + j][n_local];
    #pragma unroll
    for (int j = 0; j < 8; ++j) v1[j] = (bf16)tile[kg + 8 + j][n_local];
    bf16* dst = T + (size_t)(n0 + n_local) * 1024 + k0 + kg;
    *(bf16x8*)dst = v0;
    *(bf16x8*)(dst + 8) = v1;
}

// ---------------------------------------------------------------------------
// Kernel 2: X f32 -> bf16 cast (enables global_load_lds staging in the GEMM).
// ---------------------------------------------------------------------------
__global__ __launch_bounds__(256) void xcast_kernel(
    const float* __restrict__ Xq, const float* __restrict__ Xk, const float* __restrict__ Xv,
    bf16* __restrict__ Yq, bf16* __restrict__ Yk, bf16* __restrict__ Yv)
{
    const int z = blockIdx.z;
    const float* X = (z == 0) ? Xq : (z == 1) ? Xk : Xv;
    bf16* Y = (z == 0) ? Yq : (z == 1) ? Yk : Yv;
    const size_t i = ((size_t)blockIdx.x * 256 + threadIdx.x) * 8;
    float4 a = *(const float4*)(X + i);
    float4 b = *(const float4*)(X + i + 4);
    bf16x8 o = {(bf16)a.x, (bf16)a.y, (bf16)a.z, (bf16)a.w,
                (bf16)b.x, (bf16)b.y, (bf16)b.z, (bf16)b.w};
    *(bf16x8*)(Y + i) = o;
}

// ---------------------------------------------------------------------------
// Kernel 3: QKV projection, m97-style. 128x128 tile, 4 waves (each 64x64),
// LDS staging via global_load_lds width=16, K-step 32.
// A = Xbf [4096][1024] bf16 row-major; B = Wt [1024 n][1024 k] bf16.
// Epilogue scatters: Q,K -> [b][h][s][64]; V -> [b][h][64][s] (transposed).
// ---------------------------------------------------------------------------
__global__ __launch_bounds__(256) void qkv_gemm(
    const bf16* __restrict__ Xq, const bf16* __restrict__ Xk, const bf16* __restrict__ Xv,
    const bf16* __restrict__ Wtq, const bf16* __restrict__ Wtk, const bf16* __restrict__ Wtv,
    bf16* __restrict__ Qb, bf16* __restrict__ Kb, bf16* __restrict__ VT)
{
    const int z = blockIdx.z;
    const bf16* X = (z == 0) ? Xq : (z == 1) ? Xk : Xv;
    const bf16* Wt = (z == 0) ? Wtq : (z == 1) ? Wtk : Wtv;
    const int n0 = blockIdx.x * 128;
    const int m0 = blockIdx.y * 128;
    const int tid = threadIdx.x, w = tid >> 6, lane = tid & 63;
    const int quad = lane >> 4, c = lane & 15;
    const int wm = w & 1, wn = w >> 1;

    __shared__ bf16 As[128 * 32];
    __shared__ bf16 Bs[128 * 32];

    f32x4 acc[4][4];
    #pragma unroll
    for (int mt = 0; mt < 4; ++mt)
        #pragma unroll
        for (int nt = 0; nt < 4; ++nt) acc[mt][nt] = (f32x4){0.f, 0.f, 0.f, 0.f};

    const int lrow = lane >> 2;        // 0..15
    const int lk = (lane & 3) * 8;     // 0,8,16,24

    for (int k0 = 0; k0 < 1024; k0 += 32) {
        #pragma unroll
        for (int half = 0; half < 2; ++half) {
            const int row = half * 64 + w * 16 + lrow;
            gld_lds16(X + (size_t)(m0 + row) * 1024 + k0 + lk, As + row * 32 + lk);
            gld_lds16(Wt + (size_t)(n0 + row) * 1024 + k0 + lk, Bs + row * 32 + lk);
        }
        __syncthreads();
        bf16x8 af[4], bv[4];
        #pragma unroll
        for (int mt = 0; mt < 4; ++mt)
            af[mt] = *(const bf16x8*)&As[(wm * 64 + mt * 16 + c) * 32 + quad * 8];
        #pragma unroll
        for (int nt = 0; nt < 4; ++nt)
            bv[nt] = *(const bf16x8*)&Bs[(wn * 64 + nt * 16 + c) * 32 + quad * 8];
        #pragma unroll
        for (int mt = 0; mt < 4; ++mt)
            #pragma unroll
            for (int nt = 0; nt < 4; ++nt)
                acc[mt][nt] = MFMA16(af[mt], bv[nt], acc[mt][nt]);
        __syncthreads();
    }

    #pragma unroll
    for (int mt = 0; mt < 4; ++mt) {
        const int mb = m0 + wm * 64 + mt * 16 + quad * 4;
        const int b = mb >> 10, s = mb & 1023;
        #pragma unroll
        for (int nt = 0; nt < 4; ++nt) {
            const int n = n0 + wn * 64 + nt * 16 + c;
            const int h = n >> 6, d = n & 63;
            if (z == 2) {
                bf16x4 v = {(bf16)acc[mt][nt][0], (bf16)acc[mt][nt][1],
                            (bf16)acc[mt][nt][2], (bf16)acc[mt][nt][3]};
                *(bf16x4*)(VT + ((size_t)(b * 16 + h) * 64 + d) * 1024 + s) = v;
            } else {
                bf16* dst = ((z == 0) ? Qb : Kb) + ((size_t)(b * 16 + h) * 1024 + s) * 64 + d;
                #pragma unroll
                for (int i = 0; i < 4; ++i) dst[(size_t)i * 64] = (bf16)acc[mt][nt][i];
            }
        }
    }
}

// ---------------------------------------------------------------------------
// Kernel 4: attention, barrier-free. Per wave: 16 q-rows x all 1024 keys.
// Computes S^T tiles (MFMA with K as A-operand, Q as B-operand) so the score
// registers are directly the B-operand of the PV MFMA (half-K zero-padded
// 16x16x32) -- no LDS transpose, no __syncthreads.
// ---------------------------------------------------------------------------
__global__ __launch_bounds__(256) void attn_kernel(
    const bf16* __restrict__ Qb, const bf16* __restrict__ Kb, const bf16* __restrict__ VT,
    const float* __restrict__ lps, const unsigned char* __restrict__ mask,
    const float* __restrict__ cwp, const float* __restrict__ cbp,
    float* __restrict__ attn, bf16* __restrict__ ctxb)
{
    const int qt = blockIdx.x, h = blockIdx.y, b = blockIdx.z;
    const int tid = threadIdx.x, w = tid >> 6, lane = tid & 63;
    const int quad = lane >> 4, c = lane & 15;
    const float cw = cwp[0], cb = cbp[0];
    const int q0 = qt * 64 + w * 16;
    const size_t bh = (size_t)(b * 16 + h);

    const bf16* qptr = Qb + (bh * 1024 + q0 + c) * 64;
    const bf16x8 qf0 = *(const bf16x8*)(qptr + quad * 8);
    const bf16x8 qf1 = *(const bf16x8*)(qptr + 32 + quad * 8);
    const bf16* kbase = Kb + bh * 1024 * 64;
    const bf16* vbase = VT + bh * 64 * 1024;
    const unsigned char* mbase = mask + (size_t)b * 1024 * 1024;
    const float* lbase = lps + (size_t)(q0 + c) * 1024;
    const unsigned char* mrow = mbase + (size_t)(q0 + c) * 1024;

    // ---- pass 1: row sum of exp(score) for q = q0 + c ----
    float sum = 0.f;
    #pragma unroll 2
    for (int s0 = 0; s0 < 1024; s0 += 16) {
        const bf16* kr = kbase + (size_t)(s0 + c) * 64;
        bf16x8 kf0 = *(const bf16x8*)(kr + quad * 8);
        bf16x8 kf1 = *(const bf16x8*)(kr + 32 + quad * 8);
        f32x4 sacc = {0.f, 0.f, 0.f, 0.f};
        sacc = MFMA16(kf0, qf0, sacc);   // S^T: row = s, col = q
        sacc = MFMA16(kf1, qf1, sacc);
        float4 lp = *(const float4*)(lbase + s0 + quad * 4);
        unsigned int mw = *(const unsigned int*)(mrow + s0 + quad * 4);
        #pragma unroll
        for (int i = 0; i < 4; ++i) {
            float sc = sacc[i] * 0.125f + cw * ((const float*)&lp)[i] + cb;
            if ((mw >> (8 * i)) & 0xff) sc = -1e9f;
            sum += __expf(sc);
        }
    }
    sum += __shfl_xor(sum, 16);
    sum += __shfl_xor(sum, 32);
    const float rl = 1.0f / sum;

    // ---- pass 2: write normalized attn + PV ----
    f32x4 ctxT[4];
    #pragma unroll
    for (int dt = 0; dt < 4; ++dt) ctxT[dt] = (f32x4){0.f, 0.f, 0.f, 0.f};
    float* abase = attn + bh * 1024 * 1024 + (size_t)(q0 + c) * 1024;

    #pragma unroll 2
    for (int s0 = 0; s0 < 1024; s0 += 16) {
        const bf16* kr = kbase + (size_t)(s0 + c) * 64;
        bf16x8 kf0 = *(const bf16x8*)(kr + quad * 8);
        bf16x8 kf1 = *(const bf16x8*)(kr + 32 + quad * 8);
        f32x4 sacc = {0.f, 0.f, 0.f, 0.f};
        sacc = MFMA16(kf0, qf0, sacc);
        sacc = MFMA16(kf1, qf1, sacc);
        float4 lp = *(const float4*)(lbase + s0 + quad * 4);
        unsigned int mw = *(const unsigned int*)(mrow + s0 + quad * 4);
        float e[4];
        #pragma unroll
        for (int i = 0; i < 4; ++i) {
            float sc = sacc[i] * 0.125f + cw * ((const float*)&lp)[i] + cb;
            if ((mw >> (8 * i)) & 0xff) sc = -1e9f;
            e[i] = __expf(sc);
        }
        f32x4 st = {e[0] * rl, e[1] * rl, e[2] * rl, e[3] * rl};
        *(f32x4*)(abase + s0 + quad * 4) = st;
        // B-operand: k = quad*8 + j; j<4 -> s = s0 + quad*4 + j, j>=4 -> zero
        bf16x8 pf = {(bf16)e[0], (bf16)e[1], (bf16)e[2], (bf16)e[3],
                     (bf16)0.f, (bf16)0.f, (bf16)0.f, (bf16)0.f};
        #pragma unroll
        for (int dt = 0; dt < 4; ++dt) {
            bf16x4 vv = *(const bf16x4*)(vbase + (size_t)(dt * 16 + c) * 1024 + s0 + quad * 4);
            bf16x8 af = {vv[0], vv[1], vv[2], vv[3],
                         (bf16)0.f, (bf16)0.f, (bf16)0.f, (bf16)0.f};
            ctxT[dt] = MFMA16(af, pf, ctxT[dt]);   // ctx^T: row = d, col = q
        }
    }

    #pragma unroll
    for (int dt = 0; dt < 4; ++dt) {
        bf16x4 v = {(bf16)(ctxT[dt][0] * rl), (bf16)(ctxT[dt][1] * rl),
                    (bf16)(ctxT[dt][2] * rl), (bf16)(ctxT[dt][3] * rl)};
        *(bf16x4*)(ctxb + ((size_t)b * 1024 + q0 + c) * 1024 + h * 64 + dt * 16 + quad * 4) = v;
    }
}

// ---------------------------------------------------------------------------
// Kernel 5: out_pre = ctx @ W_fc + input_Q, same m97 GEMM structure.
// ---------------------------------------------------------------------------
__global__ __launch_bounds__(256) void fc_gemm(
    const bf16* __restrict__ ctxb, const bf16* __restrict__ Wt,
    const float* __restrict__ resid, float* __restrict__ outp)
{
    const int n0 = blockIdx.x * 128;
    const int m0 = blockIdx.y * 128;
    const int tid = threadIdx.x, w = tid >> 6, lane = tid & 63;
    const int quad = lane >> 4, c = lane & 15;
    const int wm = w & 1, wn = w >> 1;

    __shared__ bf16 As[128 * 32];
    __shared__ bf16 Bs[128 * 32];

    f32x4 acc[4][4];
    #pragma unroll
    for (int mt = 0; mt < 4; ++mt)
        #pragma unroll
        for (int nt = 0; nt < 4; ++nt) acc[mt][nt] = (f32x4){0.f, 0.f, 0.f, 0.f};

    const int lrow = lane >> 2;
    const int lk = (lane & 3) * 8;

    for (int k0 = 0; k0 < 1024; k0 += 32) {
        #pragma unroll
        for (int half = 0; half < 2; ++half) {
            const int row = half * 64 + w * 16 + lrow;
            gld_lds16(ctxb + (size_t)(m0 + row) * 1024 + k0 + lk, As + row * 32 + lk);
            gld_lds16(Wt + (size_t)(n0 + row) * 1024 + k0 + lk, Bs + row * 32 + lk);
        }
        __syncthreads();
        bf16x8 af[4], bv[4];
        #pragma unroll
        for (int mt = 0; mt < 4; ++mt)
            af[mt] = *(const bf16x8*)&As[(wm * 64 + mt * 16 + c) * 32 + quad * 8];
        #pragma unroll
        for (int nt = 0; nt < 4; ++nt)
            bv[nt] = *(const bf16x8*)&Bs[(wn * 64 + nt * 16 + c) * 32 + quad * 8];
        #pragma unroll
        for (int mt = 0; mt < 4; ++mt)
            #pragma unroll
            for (int nt = 0; nt < 4; ++nt)
                acc[mt][nt] = MFMA16(af[mt], bv[nt], acc[mt][nt]);
        __syncthreads();
    }

    #pragma unroll
    for (int mt = 0; mt < 4; ++mt) {
        const int mb = m0 + wm * 64 + mt * 16 + quad * 4;
        #pragma unroll
        for (int nt = 0; nt < 4; ++nt) {
            const int n = n0 + wn * 64 + nt * 16 + c;
            #pragma unroll
            for (int i = 0; i < 4; ++i) {
                const size_t idx = (size_t)(mb + i) * 1024 + n;
                outp[idx] = acc[mt][nt][i] + resid[idx];
            }
        }
    }
}

// ---------------------------------------------------------------------------
// Kernel 6: LayerNorm over last dim (1024).
// ---------------------------------------------------------------------------
__global__ __launch_bounds__(256) void ln_kernel(
    const float* __restrict__ xp, float* __restrict__ out)
{
    const int row = blockIdx.x, tid = threadIdx.x;
    const float* p = xp + (size_t)row * 1024 + tid * 4;
    float4 x = *(const float4*)p;
    float s = x.x + x.y + x.z + x.w;
    float q = x.x * x.x + x.y * x.y + x.z * x.z + x.w * x.w;
    #pragma unroll
    for (int off = 32; off >= 1; off >>= 1) {
        s += __shfl_down(s, off);
        q += __shfl_down(q, off);
    }
    __shared__ float sb[4], qb[4];
    const int w = tid >> 6, lane = tid & 63;
    if (lane == 0) { sb[w] = s; qb[w] = q; }
    __syncthreads();
    const float ts = sb[0] + sb[1] + sb[2] + sb[3];
    const float tq = qb[0] + qb[1] + qb[2] + qb[3];
    const float mean = ts * (1.0f / 1024.0f);
    const float var = tq * (1.0f / 1024.0f) - mean * mean;
    const float rs = rsqrtf(var + 1e-5f);
    float4 o;
    o.x = (x.x - mean) * rs; o.y = (x.y - mean) * rs;
    o.z = (x.z - mean) * rs; o.w = (x.w - mean) * rs;
    *(float4*)(out + (size_t)row * 1024 + tid * 4) = o;
}

// ---------------------------------------------------------------------------
extern "C" void kernel_launch(void* const* d_in, const int* in_sizes, int n_in,
                              void* d_out, int out_size, void* d_ws, size_t ws_size,
                              hipStream_t stream)
{
    const float* Xq  = (const float*)d_in[0];
    const float* Xk  = (const float*)d_in[1];
    const float* Xv  = (const float*)d_in[2];
    const unsigned char* mask = (const unsigned char*)d_in[3];
    const float* lps = (const float*)d_in[4];
    const float* Wq  = (const float*)d_in[5];
    const float* Wk  = (const float*)d_in[6];
    const float* Wv  = (const float*)d_in[7];
    const float* Wfc = (const float*)d_in[8];
    const float* cw  = (const float*)d_in[9];
    const float* cb  = (const float*)d_in[10];

    char* ws = (char*)d_ws;
    const size_t MB = 1024 * 1024;
    bf16* Wtq = (bf16*)(ws + 0 * MB);
    bf16* Wtk = (bf16*)(ws + 2 * MB);
    bf16* Wtv = (bf16*)(ws + 4 * MB);
    bf16* Wtf = (bf16*)(ws + 6 * MB);
    bf16* Qb  = (bf16*)(ws + 8 * MB);      // [4][16][1024][64]
    bf16* Kb  = (bf16*)(ws + 16 * MB);     // [4][16][1024][64]
    bf16* VT  = (bf16*)(ws + 24 * MB);     // [4][16][64][1024]
    // Xbf lifetime: [xcast, qkv_gemm]; ctx written by attn (later), outp by fc
    bf16* Xbq = (bf16*)(ws + 32 * MB);     // overlaps ctx region
    bf16* Xbk = (bf16*)(ws + 40 * MB);     // overlaps outp region
    bf16* Xbv = (bf16*)(ws + 48 * MB);     // overlaps outp region
    bf16* ctx = (bf16*)(ws + 32 * MB);     // [4096][1024] bf16
    float* outp = (float*)(ws + 40 * MB);  // [4096][1024] f32

    float* out_ln = (float*)d_out;
    float* attn   = (float*)d_out + (size_t)4 * MB;

    wcvt_kernel<<<dim3(16, 16, 4), 256, 0, stream>>>(Wq, Wk, Wv, Wfc, Wtq, Wtk, Wtv, Wtf);
    xcast_kernel<<<dim3(2048, 1, 3), 256, 0, stream>>>(Xq, Xk, Xv, Xbq, Xbk, Xbv);
    qkv_gemm<<<dim3(8, 32, 3), 256, 0, stream>>>(Xbq, Xbk, Xbv, Wtq, Wtk, Wtv, Qb, Kb, VT);
    attn_kernel<<<dim3(16, 16, 4), 256, 0, stream>>>(Qb, Kb, VT, lps, mask, cw, cb, attn, ctx);
    fc_gemm<<<dim3(8, 32, 1), 256, 0, stream>>>(ctx, Wtf, Xq, outp);
    ln_kernel<<<4096, 256, 0, stream>>>(outp, out_ln);
}